// Round 3
// baseline (28.161 us; speedup 1.0000x reference)
//
#include <hip/hip_runtime.h>

// SeparableWeightedConv: depthwise 1D conv (K=9, pad=4) with per-(b,l,k)
// distance weights dw = max(1 - dist/sigma, 0), shared across channels.
// R2: occupancy attack. Coord windows staged in LDS (kills the 36-reg coord
// arrays -> VGPR peak ~80 -> ~6 waves/SIMD), CH=4 -> 2048 blocks. Keeps the
// R1 one-deep x prefetch in the channel loop.

#define BB 8
#define CC 128
#define NN 8192
#define KK 9

constexpr int CH      = 4;            // channels per block
constexpr int CGROUPS = CC / CH;      // 32
constexpr int LTILE   = 1024;         // l positions per block (256 thr x 4)
constexpr int LTILES  = NN / LTILE;   // 8
constexpr int THREADS = 256;
constexpr int LSPAN   = LTILE + 8;    // staged window per dim (floats)
constexpr int SLOTS   = LSPAN / 4;    // 258 float4 slots per dim

__device__ __forceinline__ void load12(const float* __restrict__ p, int l0, bool interior,
                                       float4& A, float4& B, float4& C) {
    if (interior) {
        A = *(const float4*)(p + l0 - 4);
        B = *(const float4*)(p + l0);
        C = *(const float4*)(p + l0 + 4);
    } else {
        float t[12];
        #pragma unroll
        for (int j = 0; j < 12; ++j) {
            int q = l0 - 4 + j;
            t[j] = (q >= 0 && q < NN) ? p[q] : 0.0f;   // zero-pad (x path)
        }
        A = make_float4(t[0], t[1], t[2], t[3]);
        B = make_float4(t[4], t[5], t[6], t[7]);
        C = make_float4(t[8], t[9], t[10], t[11]);
    }
}

__global__ __launch_bounds__(THREADS)
void sepwconv_kernel(const float* __restrict__ x,
                     const float* __restrict__ coords,
                     const float* __restrict__ sigma,
                     const float* __restrict__ weight,
                     float* __restrict__ out)
{
    __shared__ float lds[3 * LSPAN];   // 12384 B

    const int bid = blockIdx.x;
    const int cg  = bid % CGROUPS;
    const int lt  = (bid / CGROUPS) % LTILES;
    const int b   = bid / (CGROUPS * LTILES);
    const int t   = threadIdx.x;
    const int blk_l0 = lt * LTILE;
    const int l0  = blk_l0 + t * 4;

    // ---- stage coord windows (3 dims, l in [blk_l0-4, blk_l0+LTILE+4)) ----
    const float* cbase = coords + (size_t)b * 3 * NN;
    for (int s = t; s < 3 * SLOTS; s += THREADS) {
        const int dim  = s / SLOTS;
        const int slot = s - dim * SLOTS;
        const int g0   = blk_l0 - 4 + slot * 4;
        const float* src = cbase + (size_t)dim * NN;
        float4 v;
        if (g0 >= 0 && g0 + 3 < NN) {
            v = *(const float4*)(src + g0);
        } else {
            float tv[4];
            #pragma unroll
            for (int j = 0; j < 4; ++j) {
                int g = g0 + j;
                g = g < 0 ? 0 : (g >= NN ? NN - 1 : g);  // clamp: OOB taps hit x==0
                tv[j] = src[g];
            }
            v = make_float4(tv[0], tv[1], tv[2], tv[3]);
        }
        *(float4*)(&lds[dim * LSPAN + slot * 4]) = v;
    }

    const bool interior = (l0 >= 4) && (l0 + 8 <= NN);
    const float inv_sigma = 1.0f / sigma[0];

    // issue channel-0 x loads before the sqrt chain (overlap)
    const float* xbase = x + ((size_t)b * CC + cg * CH) * NN;
    float4 XA, XB, XC;
    load12(xbase, l0, interior, XA, XB, XC);

    __syncthreads();

    // ---- dw[4][K]: accumulate squared distance dim-by-dim from LDS ----
    float dw[4][KK];
    #pragma unroll
    for (int jl = 0; jl < 4; ++jl)
        #pragma unroll
        for (int k = 0; k < KK; ++k) dw[jl][k] = 0.f;

    #pragma unroll
    for (int dim = 0; dim < 3; ++dim) {
        const float* wp = &lds[dim * LSPAN + t * 4];   // wp[j] = coord(l0-4+j)
        float4 A  = *(const float4*)(wp);
        float4 Bq = *(const float4*)(wp + 4);
        float4 Cq = *(const float4*)(wp + 8);
        const float wv[12] = {A.x,A.y,A.z,A.w, Bq.x,Bq.y,Bq.z,Bq.w, Cq.x,Cq.y,Cq.z,Cq.w};
        #pragma unroll
        for (int jl = 0; jl < 4; ++jl) {
            const float ctr = wv[jl + 4];
            #pragma unroll
            for (int k = 0; k < KK; ++k) {
                const float d = wv[jl + k] - ctr;
                dw[jl][k] = fmaf(d, d, dw[jl][k]);
            }
        }
    }
    #pragma unroll
    for (int jl = 0; jl < 4; ++jl)
        #pragma unroll
        for (int k = 0; k < KK; ++k) {
            const float dist = sqrtf(dw[jl][k]);       // sqrt(0)==0 matches ref
            dw[jl][k] = fmaxf(fmaf(-inv_sigma, dist, 1.0f), 0.0f);
        }

    // ---- software-pipelined channel loop ----
    #pragma unroll 1
    for (int i = 0; i < CH; ++i) {
        float4 NA, NB, NC;
        if (i + 1 < CH) load12(xbase + (size_t)(i + 1) * NN, l0, interior, NA, NB, NC);

        const int c = cg * CH + i;
        const float* wr = weight + c * KK;    // wave-uniform -> s_load
        float w[KK];
        #pragma unroll
        for (int k = 0; k < KK; ++k) w[k] = wr[k];

        const float xv[12] = {XA.x,XA.y,XA.z,XA.w, XB.x,XB.y,XB.z,XB.w, XC.x,XC.y,XC.z,XC.w};

        float acc[4] = {0.f, 0.f, 0.f, 0.f};
        #pragma unroll
        for (int jl = 0; jl < 4; ++jl) {
            #pragma unroll
            for (int k = 0; k < KK; ++k) {
                acc[jl] = fmaf(xv[jl + k] * dw[jl][k], w[k], acc[jl]);
            }
        }

        float4 o; o.x = acc[0]; o.y = acc[1]; o.z = acc[2]; o.w = acc[3];
        *(float4*)(out + ((size_t)b * CC + c) * NN + l0) = o;

        if (i + 1 < CH) { XA = NA; XB = NB; XC = NC; }
    }
}

extern "C" void kernel_launch(void* const* d_in, const int* in_sizes, int n_in,
                              void* d_out, int out_size, void* d_ws, size_t ws_size,
                              hipStream_t stream) {
    const float* x      = (const float*)d_in[0];
    const float* coords = (const float*)d_in[1];
    const float* sigma  = (const float*)d_in[2];
    const float* weight = (const float*)d_in[3];
    float* out = (float*)d_out;

    dim3 grid(BB * LTILES * CGROUPS);   // 8 * 8 * 32 = 2048 blocks
    sepwconv_kernel<<<grid, THREADS, 0, stream>>>(x, coords, sigma, weight, out);
}

// Round 4
// 26.145 us; speedup vs baseline: 1.0771x; 1.0771x over previous
//
#include <hip/hip_runtime.h>

// SeparableWeightedConv R3: two-kernel split.
//  Kernel A: dw[b][k][l] = max(1 - dist(l,k)/sigma, 0) into d_ws (2.36 MB).
//  Kernel B: pure streaming depthwise conv; dw loaded as 9 coalesced float4
//            loads per thread, kept in regs across the channel loop.
// Fallback to fused single-kernel (R1) if ws_size is too small.

#define BB 8
#define CC 128
#define NN 8192
#define KK 9

constexpr int THREADS = 256;

// ---------------- Kernel A: distance weights ----------------
__global__ __launch_bounds__(THREADS)
void dw_kernel(const float* __restrict__ coords,
               const float* __restrict__ sigma,
               float* __restrict__ dwbuf)
{
    const int g = blockIdx.x * THREADS + threadIdx.x;   // [0, BB*NN)
    const int b = g >> 13;                              // / NN
    const int l = g & (NN - 1);
    const float inv_sigma = 1.0f / sigma[0];

    const float* cb = coords + (size_t)b * 3 * NN;
    float cv[3][KK];
    #pragma unroll
    for (int dim = 0; dim < 3; ++dim) {
        const float* src = cb + (size_t)dim * NN;
        #pragma unroll
        for (int j = 0; j < KK; ++j) {
            int p = l + j - 4;
            p = p < 0 ? 0 : (p >= NN ? NN - 1 : p);     // clamp: OOB taps hit x==0
            cv[dim][j] = src[p];
        }
    }
    #pragma unroll
    for (int k = 0; k < KK; ++k) {
        const float dx = cv[0][k] - cv[0][4];
        const float dy = cv[1][k] - cv[1][4];
        const float dz = cv[2][k] - cv[2][4];
        const float sq = fmaf(dx, dx, fmaf(dy, dy, dz * dz));
        const float dist = sqrtf(sq);                   // sqrt(0)==0 matches ref
        dwbuf[((size_t)b * KK + k) * NN + l] = fmaxf(fmaf(-inv_sigma, dist, 1.0f), 0.0f);
    }
}

// ---------------- Kernel B: streaming conv ----------------
constexpr int CH      = 4;            // channels per block
constexpr int CGROUPS = CC / CH;      // 32
constexpr int LTILE   = 1024;         // 256 thr x 4 l
constexpr int LTILES  = NN / LTILE;   // 8

__device__ __forceinline__ void load12(const float* __restrict__ p, int l0, bool interior,
                                       float4& A, float4& B, float4& C) {
    if (interior) {
        A = *(const float4*)(p + l0 - 4);
        B = *(const float4*)(p + l0);
        C = *(const float4*)(p + l0 + 4);
    } else {
        float t[12];
        #pragma unroll
        for (int j = 0; j < 12; ++j) {
            int q = l0 - 4 + j;
            t[j] = (q >= 0 && q < NN) ? p[q] : 0.0f;    // zero-pad (x path)
        }
        A = make_float4(t[0], t[1], t[2], t[3]);
        B = make_float4(t[4], t[5], t[6], t[7]);
        C = make_float4(t[8], t[9], t[10], t[11]);
    }
}

__global__ __launch_bounds__(THREADS)
void conv_kernel(const float* __restrict__ x,
                 const float* __restrict__ dwbuf,
                 const float* __restrict__ weight,
                 float* __restrict__ out)
{
    const int bid = blockIdx.x;
    const int cg  = bid % CGROUPS;
    const int lt  = (bid / CGROUPS) % LTILES;
    const int b   = bid / (CGROUPS * LTILES);
    const int t   = threadIdx.x;
    const int l0  = lt * LTILE + t * 4;

    const bool interior = (l0 >= 4) && (l0 + 8 <= NN);

    // dw loads: 9 coalesced float4 loads, independent -> high MLP at block start
    float4 dwq[KK];
    #pragma unroll
    for (int k = 0; k < KK; ++k)
        dwq[k] = *(const float4*)(dwbuf + ((size_t)b * KK + k) * NN + l0);

    // channel-0 x loads issued alongside
    const float* xbase = x + ((size_t)b * CC + cg * CH) * NN;
    float4 XA, XB, XC;
    load12(xbase, l0, interior, XA, XB, XC);

    #pragma unroll 1
    for (int i = 0; i < CH; ++i) {
        float4 NA, NB, NC;
        if (i + 1 < CH) load12(xbase + (size_t)(i + 1) * NN, l0, interior, NA, NB, NC);

        const int c = cg * CH + i;
        const float* wr = weight + c * KK;              // wave-uniform -> s_load
        float w[KK];
        #pragma unroll
        for (int k = 0; k < KK; ++k) w[k] = wr[k];

        const float xv[12] = {XA.x,XA.y,XA.z,XA.w, XB.x,XB.y,XB.z,XB.w, XC.x,XC.y,XC.z,XC.w};

        float4 acc = make_float4(0.f, 0.f, 0.f, 0.f);
        #pragma unroll
        for (int k = 0; k < KK; ++k) {
            acc.x = fmaf(xv[0 + k] * dwq[k].x, w[k], acc.x);
            acc.y = fmaf(xv[1 + k] * dwq[k].y, w[k], acc.y);
            acc.z = fmaf(xv[2 + k] * dwq[k].z, w[k], acc.z);
            acc.w = fmaf(xv[3 + k] * dwq[k].w, w[k], acc.w);
        }
        *(float4*)(out + ((size_t)b * CC + c) * NN + l0) = acc;

        if (i + 1 < CH) { XA = NA; XB = NB; XC = NC; }
    }
}

// ---------------- Fallback: fused single kernel (R1) ----------------
__global__ __launch_bounds__(THREADS)
void fused_kernel(const float* __restrict__ x,
                  const float* __restrict__ coords,
                  const float* __restrict__ sigma,
                  const float* __restrict__ weight,
                  float* __restrict__ out)
{
    const int bid = blockIdx.x;
    const int cg  = bid % 16;
    const int lt  = (bid / 16) % 8;
    const int b   = bid / (16 * 8);
    const int t   = threadIdx.x;
    const int l0  = lt * 1024 + t * 4;
    const bool interior = (l0 >= 4) && (l0 + 8 <= NN);
    const float inv_sigma = 1.0f / sigma[0];

    const float* cx = coords + (size_t)(b * 3 + 0) * NN;
    const float* cy = coords + (size_t)(b * 3 + 1) * NN;
    const float* cz = coords + (size_t)(b * 3 + 2) * NN;

    float cxv[12], cyv[12], czv[12];
    #pragma unroll
    for (int j = 0; j < 12; ++j) {
        int p = l0 - 4 + j;
        p = p < 0 ? 0 : (p >= NN ? NN - 1 : p);
        cxv[j] = cx[p]; cyv[j] = cy[p]; czv[j] = cz[p];
    }

    const float* xbase = x + ((size_t)b * CC + cg * 8) * NN;
    float4 XA, XB, XC;
    load12(xbase, l0, interior, XA, XB, XC);

    float dw[4][KK];
    #pragma unroll
    for (int jl = 0; jl < 4; ++jl) {
        const float ccx = cxv[jl + 4], ccy = cyv[jl + 4], ccz = czv[jl + 4];
        #pragma unroll
        for (int k = 0; k < KK; ++k) {
            const float dx = cxv[jl + k] - ccx;
            const float dy = cyv[jl + k] - ccy;
            const float dz = czv[jl + k] - ccz;
            const float sq = fmaf(dx, dx, fmaf(dy, dy, dz * dz));
            dw[jl][k] = fmaxf(fmaf(-inv_sigma, sqrtf(sq), 1.0f), 0.0f);
        }
    }

    #pragma unroll 1
    for (int i = 0; i < 8; ++i) {
        float4 NA, NB, NC;
        if (i + 1 < 8) load12(xbase + (size_t)(i + 1) * NN, l0, interior, NA, NB, NC);
        const int c = cg * 8 + i;
        const float* wr = weight + c * KK;
        float w[KK];
        #pragma unroll
        for (int k = 0; k < KK; ++k) w[k] = wr[k];
        const float xv[12] = {XA.x,XA.y,XA.z,XA.w, XB.x,XB.y,XB.z,XB.w, XC.x,XC.y,XC.z,XC.w};
        float acc[4] = {0.f, 0.f, 0.f, 0.f};
        #pragma unroll
        for (int jl = 0; jl < 4; ++jl)
            #pragma unroll
            for (int k = 0; k < KK; ++k)
                acc[jl] = fmaf(xv[jl + k] * dw[jl][k], w[k], acc[jl]);
        float4 o; o.x = acc[0]; o.y = acc[1]; o.z = acc[2]; o.w = acc[3];
        *(float4*)(out + ((size_t)b * CC + c) * NN + l0) = o;
        if (i + 1 < 8) { XA = NA; XB = NB; XC = NC; }
    }
}

extern "C" void kernel_launch(void* const* d_in, const int* in_sizes, int n_in,
                              void* d_out, int out_size, void* d_ws, size_t ws_size,
                              hipStream_t stream) {
    const float* x      = (const float*)d_in[0];
    const float* coords = (const float*)d_in[1];
    const float* sigma  = (const float*)d_in[2];
    const float* weight = (const float*)d_in[3];
    float* out = (float*)d_out;

    const size_t dw_bytes = (size_t)BB * KK * NN * sizeof(float);   // 2.36 MB
    if (ws_size >= dw_bytes) {
        float* dwbuf = (float*)d_ws;
        dw_kernel<<<dim3(BB * NN / THREADS), THREADS, 0, stream>>>(coords, sigma, dwbuf);
        conv_kernel<<<dim3(BB * LTILES * CGROUPS), THREADS, 0, stream>>>(x, dwbuf, weight, out);
    } else {
        fused_kernel<<<dim3(BB * 8 * 16), THREADS, 0, stream>>>(x, coords, sigma, weight, out);
    }
}